// Round 6
// baseline (310.489 us; speedup 1.0000x reference)
//
#include <hip/hip_runtime.h>

// out[c,n,o] = sum_i x[c,n,i] * W[model_idx[c],i,o] + B[int(t[c]*31),o]
// x[64,2048,256] f32, W[64,256,256] f32, B[32,256] f32, out f32.
//
// v7: BARRIER-FREE per-wave pipelines. v6's NaN: __launch_bounds__(512,6)
// forced spills; scratch ops count vmcnt -> static counts broke -> race.
// Rule: counted-vmcnt schedules require a no-spill register budget.
// New partition: block = 128 rows x 64 cols, 4 waves each own 32x64.
// Each wave stages rows [w*32, w*32+32) via global_load_lds AND reads only
// those rows -> A-tile is wave-private -> NO s_barrier anywhere. Each wave
// runs its own depth-2 pipeline (3 bufs) with v5's proven static counts
// (stage=4 ops, B=4 ops): VTOP drains STAGE(s), VMFMA drains B(s).
// WAR on buffer reuse is covered by the wave's own lgkmcnt(0) at step top.
// VGPR ~100 (acc 32 + b 32 + f 16) < cap 170 at (256,3) -> no spill.
// 12 waves/CU (LDS 144KB) of independent pipelines vs v5's 8 lockstepped.
// wt_k prepass kept: Wt[c][n][k] bf16; B-frags 16B L2-resident, 4x redundant
// across m-waves (L2 absorbs). 4 n-quarter blocks share X tiles via L2/L3,
// same-XCD by chunked remap (4096%8==0, bijective).

#define M_PTS 2048
#define K_DIM 256
#define N_DIM 256
#define BT_STRIDE 264
#define WT_BYTES ((size_t)64 * K_DIM * N_DIM * 2)

typedef float floatx4 __attribute__((ext_vector_type(4)));
typedef unsigned uintx4 __attribute__((ext_vector_type(4)));
typedef __bf16 bf16x4 __attribute__((ext_vector_type(4)));
typedef __bf16 bf16x8 __attribute__((ext_vector_type(8)));

typedef __attribute__((address_space(3))) void lds_void;
typedef const __attribute__((address_space(1))) void gbl_void;

__device__ __forceinline__ __bf16 cvt_bf16(float f) {
  unsigned u = __builtin_bit_cast(unsigned, f);
  unsigned r = (u + 0x7FFFu + ((u >> 16) & 1u)) >> 16;
  return __builtin_bit_cast(__bf16, (unsigned short)r);
}

__device__ __forceinline__ unsigned cvt_pk(float lo, float hi) {
  // v_cvt_pk_bf16_f32: RNE, packs {lo,hi} -> {bits15:0, bits31:16}
  unsigned d;
  asm("v_cvt_pk_bf16_f32 %0, %1, %2" : "=v"(d) : "v"(lo), "v"(hi));
  return d;
}

// ---- pre-pass: gather + transpose + cvt W into workspace --------------------
__global__ __launch_bounds__(256) void wt_k(const float* __restrict__ W,
                                            const int* __restrict__ MI,
                                            __bf16* __restrict__ Wt) {
  __shared__ float tile[64][65];
  const int bid = blockIdx.x;
  const int c  = bid >> 4;
  const int kt = (bid >> 2) & 3;
  const int nt = bid & 3;
  const float* __restrict__ src =
      W + (size_t)MI[c] * (K_DIM * N_DIM) + (size_t)(kt * 64) * N_DIM + nt * 64;
  __bf16* __restrict__ dst =
      Wt + (size_t)c * (K_DIM * N_DIM) + (size_t)(nt * 64) * K_DIM + kt * 64;
  const int tid = threadIdx.x;
  {
    const int nl = tid & 63, kl0 = tid >> 6;
#pragma unroll
    for (int u = 0; u < 16; ++u)
      tile[kl0 + u * 4][nl] = src[(size_t)(kl0 + u * 4) * N_DIM + nl];
  }
  __syncthreads();
  {
    const int kl = tid & 63, nl0 = tid >> 6;
#pragma unroll
    for (int u = 0; u < 16; ++u)
      dst[(size_t)(nl0 + u * 4) * K_DIM + kl] = cvt_bf16(tile[kl][nl0 + u * 4]);
  }
}

// ---- main: 4 independent per-wave pipelines, zero barriers -----------------
// 4096 blocks: (c, mg, nq); each block 128 rows x 64 cols; wave w owns
// rows [w*32, w*32+32) x all 64 cols.
__global__ __launch_bounds__(256, 3) void gemm_k(const float* __restrict__ X,
                                                 const float* __restrict__ T,
                                                 const __bf16* __restrict__ Wt,
                                                 const float* __restrict__ Bb,
                                                 float* __restrict__ Out) {
  __shared__ float As[3][128 * 32];  // 16 KB each, 48 KB total

  // XCD-chunked remap: 4096 blocks, 512 logical wgs per XCD; the 4
  // n-quarters of one (c,mg) stay adjacent -> same XCD L2 for X dedup.
  const int bid = blockIdx.x;
  const int wg  = ((bid & 7) << 9) | (bid >> 3);
  const int c   = wg >> 6;
  const int mg  = (wg >> 2) & 15;
  const int nq  = wg & 3;
  const int n0  = nq * 64;
  const int m0  = mg * 128;

  const int tid  = threadIdx.x;
  const int lane = tid & 63;
  const int w    = tid >> 6;   // wave 0..3 = m-position
  const int r    = lane & 15;  // fragment row/col
  const int kg   = lane >> 4;  // k-group 0..3

  const float*  __restrict__ Xc = X  + (size_t)c * (M_PTS * K_DIM);
  const __bf16* __restrict__ Wc = Wt + (size_t)c * (K_DIM * N_DIM);

  // staging: wave w rows [w*32, w*32+32), 4 issues of 8 rows x 128B.
  // Source chunk pre-permuted (lc^l8); read applies same XOR (row&7 == l8).
  const int l8 = lane >> 3;
  const int lc = lane & 7;
  const float* __restrict__ xbase =
      Xc + (size_t)(m0 + w * 32 + l8) * K_DIM + ((lc ^ l8) << 2);
  const int lbase = (w * 32 + l8) * 32 + lc * 4;  // float index into As[buf]

#define STAGE(kt_, buf_)                                                      \
  {                                                                           \
    _Pragma("unroll") for (int u = 0; u < 4; ++u) {                           \
      __builtin_amdgcn_global_load_lds(                                       \
          (gbl_void*)(xbase + (size_t)u * 8 * K_DIM + (kt_) * 32),            \
          (lds_void*)(&As[buf_][lbase + u * 256]), 16, 0, 0);                 \
    }                                                                         \
  }

  // B fragment pointers: Wt row (n) is K-contiguous bf16; 16B per (j,kt).
  // All 4 waves load the same 64 cols (redundant, L2-resident).
  const __bf16* __restrict__ wb[4];
#pragma unroll
  for (int j = 0; j < 4; ++j)
    wb[j] = Wc + (size_t)(n0 + j * 16 + r) * K_DIM + kg * 8;

  floatx4 acc[2][4] = {};
  uintx4 b0[4], b1[4];

  // ---- prologue: STAGE(0), STAGE(1), B(0) -- pinned order (12 in flight) --
  STAGE(0, 0);
  asm volatile("" ::: "memory");
  STAGE(1, 1);
  asm volatile("" ::: "memory");
#pragma unroll
  for (int j = 0; j < 4; ++j)
    asm volatile("global_load_dwordx4 %0, %1, off"
                 : "=&v"(b0[j]) : "v"(wb[j]) : "memory");

  // ---- 8 hand-unrolled steps, per-wave counted waits, NO barriers ----
  // VTOP: after STAGE(s) come B(s-1)[4]+STAGE(s+1)[4]+B(s)[4]=12 (s=0:8, s=7:8)
  // VMFMA: after B(s) come STAGE(s+2)[4]+B(s+1)[4]=8 (s=6:4, s=7:0)
#define STEP(s_, VTOP_, VMFMA_, BC_, BN_)                                     \
  {                                                                           \
    asm volatile("s_waitcnt vmcnt(" #VTOP_ ") lgkmcnt(0)" ::: "memory");      \
    __builtin_amdgcn_sched_barrier(0);                                        \
    if ((s_) + 2 < 8) STAGE((s_) + 2, ((s_) + 2) % 3);                        \
    asm volatile("" ::: "memory");                                            \
    if ((s_) + 1 < 8) {                                                       \
      _Pragma("unroll") for (int j = 0; j < 4; ++j)                           \
        asm volatile("global_load_dwordx4 %0, %1, off"                        \
                     : "=&v"(BN_[j])                                          \
                     : "v"(wb[j] + ((s_) + 1) * 32) : "memory");              \
    }                                                                         \
    const float* __restrict__ Ab = As[(s_) % 3];                              \
    floatx4 f0[2], f1[2];                                                     \
    _Pragma("unroll") for (int i = 0; i < 2; ++i) {                           \
      const int row_ = w * 32 + i * 16 + r;                                   \
      const int p0_  = ((kg * 32) ^ ((r & 7) << 4)) >> 2;                     \
      f0[i] = *(const floatx4*)&Ab[row_ * 32 + p0_];                          \
      f1[i] = *(const floatx4*)&Ab[row_ * 32 + (p0_ ^ 4)];                    \
    }                                                                         \
    asm volatile("s_waitcnt vmcnt(" #VMFMA_ ") lgkmcnt(0)" ::: "memory");     \
    __builtin_amdgcn_sched_barrier(0);                                        \
    _Pragma("unroll") for (int i = 0; i < 2; ++i) {                           \
      uintx4 q;                                                               \
      q.x = cvt_pk(f0[i].x, f0[i].y);                                         \
      q.y = cvt_pk(f0[i].z, f0[i].w);                                         \
      q.z = cvt_pk(f1[i].x, f1[i].y);                                         \
      q.w = cvt_pk(f1[i].z, f1[i].w);                                         \
      const bf16x8 av = __builtin_bit_cast(bf16x8, q);                        \
      _Pragma("unroll") for (int j = 0; j < 4; ++j)                           \
        acc[i][j] = __builtin_amdgcn_mfma_f32_16x16x32_bf16(                  \
            av, __builtin_bit_cast(bf16x8, BC_[j]), acc[i][j], 0, 0, 0);      \
    }                                                                         \
  }

  STEP(0,  8, 8, b0, b1);
  STEP(1, 12, 8, b1, b0);
  STEP(2, 12, 8, b0, b1);
  STEP(3, 12, 8, b1, b0);
  STEP(4, 12, 8, b0, b1);
  STEP(5, 12, 8, b1, b0);
  STEP(6, 12, 4, b0, b1);
  STEP(7,  8, 0, b1, b0);
#undef STEP
#undef STAGE

  // ---- epilogue: bias loads here (keeps loop vmcnt counts clean) ----
  int bidx = (int)(T[c] * 31.0f);
  bidx = bidx < 0 ? 0 : (bidx > 31 ? 31 : bidx);
  const float* __restrict__ brow = Bb + bidx * N_DIM + n0;
  float bv[4];
#pragma unroll
  for (int j = 0; j < 4; ++j) bv[j] = brow[j * 16 + r];

  // C/D layout: col=lane&15, row=(lane>>4)*4+reg [m89/m91]
  float* __restrict__ Oc = Out + (size_t)c * (M_PTS * N_DIM);
#pragma unroll
  for (int i = 0; i < 2; ++i) {
#pragma unroll
    for (int j = 0; j < 4; ++j) {
      const int col = n0 + j * 16 + r;
#pragma unroll
      for (int v = 0; v < 4; ++v) {
        const int row = m0 + w * 32 + i * 16 + kg * 4 + v;
        Oc[(size_t)row * N_DIM + col] = acc[i][j][v] + bv[j];
      }
    }
  }
}

// ---- fallback: previous proven kernel (used only if workspace too small) ---
__global__ __launch_bounds__(256) void fused_k(
    const float* __restrict__ X, const float* __restrict__ T,
    const int* __restrict__ MI, const float* __restrict__ W,
    const float* __restrict__ Bb, float* __restrict__ Out) {
  __shared__ __bf16 As[128 * 32];
  __shared__ __bf16 Bt[128 * BT_STRIDE];

  const int bid = blockIdx.x;
  const int c   = bid >> 4;
  const int mg  = (bid >> 1) & 7;
  const int nt  = bid & 1;
  const int n0  = nt * 128;

  const float* __restrict__ Xc = X + (size_t)c * (M_PTS * K_DIM);
  const float* __restrict__ Wc = W + (size_t)MI[c] * (K_DIM * N_DIM);

  const int tid  = threadIdx.x;
  const int lane = tid & 63;
  const int w    = tid >> 6;
  const int wm   = w & 1;
  const int wn   = w >> 1;
  const int r    = lane & 15;
  const int kg   = lane >> 4;

  {
    const int n  = tid & 127;
    const int kq = tid >> 7;
    const float* __restrict__ src = Wc + (size_t)(kq * 128) * N_DIM + n0 + n;
    __bf16* __restrict__ dst = &Bt[n * BT_STRIDE + kq * 128];
#pragma unroll 4
    for (int u = 0; u < 32; ++u) {
      bf16x4 v;
      v.x = cvt_bf16(src[(size_t)(u * 4 + 0) * N_DIM]);
      v.y = cvt_bf16(src[(size_t)(u * 4 + 1) * N_DIM]);
      v.z = cvt_bf16(src[(size_t)(u * 4 + 2) * N_DIM]);
      v.w = cvt_bf16(src[(size_t)(u * 4 + 3) * N_DIM]);
      *(bf16x4*)&dst[u * 4] = v;
    }
  }

  const int sm  = tid >> 1;
  const int skh = (tid & 1) * 16;
  const float* __restrict__ xrow = Xc + skh;
  __bf16* __restrict__ adst = &As[sm * 32 + skh];

  int bidx = (int)(T[c] * 31.0f);
  bidx = bidx < 0 ? 0 : (bidx > 31 ? 31 : bidx);
  const float* __restrict__ brow = Bb + bidx * N_DIM + n0 + wn * 64;
  float bv[4];
#pragma unroll
  for (int j = 0; j < 4; ++j) bv[j] = brow[j * 16 + r];

  float* __restrict__ Oc = Out + (size_t)c * (M_PTS * N_DIM);

  for (int mt2 = 0; mt2 < 2; ++mt2) {
    const int m0 = mg * 256 + mt2 * 128;
    const float* __restrict__ xsrc = xrow + (size_t)(m0 + sm) * K_DIM;
    floatx4 acc[4][4] = {};

    for (int kt = 0; kt < 8; ++kt) {
      const int k0 = kt * 32;
      __syncthreads();
      {
        floatx4 f0 = *(const floatx4*)(xsrc + k0 + 0);
        floatx4 f1 = *(const floatx4*)(xsrc + k0 + 4);
        floatx4 f2 = *(const floatx4*)(xsrc + k0 + 8);
        floatx4 f3 = *(const floatx4*)(xsrc + k0 + 12);
        bf16x8 h0, h1;
#pragma unroll
        for (int v = 0; v < 4; ++v) {
          h0[v]     = cvt_bf16(f0[v]);
          h0[v + 4] = cvt_bf16(f1[v]);
          h1[v]     = cvt_bf16(f2[v]);
          h1[v + 4] = cvt_bf16(f3[v]);
        }
        *(bf16x8*)&adst[0] = h0;
        *(bf16x8*)&adst[8] = h1;
      }
      __syncthreads();

      bf16x8 a[4], b[4];
#pragma unroll
      for (int i = 0; i < 4; ++i)
        a[i] = *(const bf16x8*)&As[(wm * 64 + i * 16 + r) * 32 + kg * 8];
#pragma unroll
      for (int j = 0; j < 4; ++j)
        b[j] = *(const bf16x8*)&Bt[(wn * 64 + j * 16 + r) * BT_STRIDE + k0 + kg * 8];
#pragma unroll
      for (int i = 0; i < 4; ++i)
#pragma unroll
        for (int j = 0; j < 4; ++j)
          acc[i][j] = __builtin_amdgcn_mfma_f32_16x16x32_bf16(a[i], b[j], acc[i][j], 0, 0, 0);
    }

#pragma unroll
    for (int i = 0; i < 4; ++i) {
#pragma unroll
      for (int j = 0; j < 4; ++j) {
        const int col = n0 + wn * 64 + j * 16 + r;
#pragma unroll
        for (int v = 0; v < 4; ++v) {
          const int row = m0 + wm * 64 + i * 16 + kg * 4 + v;
          Oc[(size_t)row * N_DIM + col] = acc[i][j][v] + bv[j];
        }
      }
    }
  }
}

extern "C" void kernel_launch(void* const* d_in, const int* in_sizes, int n_in,
                              void* d_out, int out_size, void* d_ws, size_t ws_size,
                              hipStream_t stream) {
  const float* X   = (const float*)d_in[0];  // x [64,2048,256]
  const float* T   = (const float*)d_in[1];  // t [64]
  const int* MI    = (const int*)d_in[2];    // model_idx [64]
  const float* W   = (const float*)d_in[3];  // W [64,256,256]
  const float* Bb  = (const float*)d_in[4];  // B [32,256]
  float* Out       = (float*)d_out;

  if (ws_size >= WT_BYTES && d_ws != nullptr) {
    __bf16* Wt = (__bf16*)d_ws;
    wt_k<<<dim3(1024), dim3(256), 0, stream>>>(W, MI, Wt);
    gemm_k<<<dim3(4096), dim3(256), 0, stream>>>(X, T, Wt, Bb, Out);
  } else {
    fused_k<<<dim3(1024), dim3(256), 0, stream>>>(X, T, MI, W, Bb, Out);
  }
}